// Round 5
// baseline (583.167 us; speedup 1.0000x reference)
//
#include <hip/hip_runtime.h>
#include <math.h>

#define B 8
#define N 2048
#define C 16
#define HID 128
#define NRF 16384      // 128*128
#define MAXLEN 8
#define MAXCH 2048
#define NBLK 512       // 2 blocks/CU co-resident (LDS 38.4KB x2 <= 160KB, VGPR<=128)

#define MAGIC1 0x1357BD13
#define MAGIC2 0x2468ACE2

typedef __attribute__((ext_vector_type(4))) float f32x4;  // native vec for nontemporal

__device__ __forceinline__ float sigf(float x) { return 1.f / (1.f + expf(-x)); }

// Poison-tolerant grid barrier (R13-verified under graph capture): block
// publishes flags[bid]=magic (release, agent scope); threads 0..NBLK-1
// spin-acquire on flags[tid]. Distinct magics per barrier -> stale values
// (poison or previous launch's K2) never alias the awaited magic.
__device__ __forceinline__ void gridbar(int* flags, int magic) {
    __syncthreads();
    if (threadIdx.x == 0) {
        __threadfence();   // release all prior global writes (agent scope)
        __hip_atomic_store(&flags[blockIdx.x], magic, __ATOMIC_RELEASE,
                           __HIP_MEMORY_SCOPE_AGENT);
    }
    if (threadIdx.x < NBLK) {
        while (__hip_atomic_load(&flags[threadIdx.x], __ATOMIC_ACQUIRE,
                                 __HIP_MEMORY_SCOPE_AGENT) != magic)
            __builtin_amdgcn_s_sleep(1);
    }
    __syncthreads();
    __threadfence();       // acquire side: drop stale cached lines
}

// LDS union: pre phase uses 16-bit-packed counters (32 KB); main phase uses
// gate0 weight stage (32 KB) + recur state (~6 KB). Max ~38 KB -> 2 blocks/CU.
struct SmemPre {
    unsigned int cnt16[NRF / 2];       // two 16-bit counts per word (<=2048 each)
    int nch, nmul;
};
struct SmemMain {
    float ls_w[C * 512];               // 32 KB gate0 weights
    float ls_b[512];
    int   l_pk[32];
    float h_s[HID], c_s[HID], x_s[16], g_s[512];
};
union Smem { SmemPre pre; SmemMain mn; };

// R14: fused v2. R13 post-mortem: wcol[128] spilled (VGPR_Count=112 < 128
// needed) -> scratch-bound recur; NBLK=256 halved recur parallelism. Fixes:
// stream w_hh_T from L2 (proven 3-kernel pattern), NBLK=512 (2 blocks/CU,
// 64 recur slots/batch ~= 2 serial chains), launch_bounds(512,4) caps VGPR
// at 128 >= measured 112 so nothing new spills.
__global__ __launch_bounds__(512, 4) void k_all(
    const float* __restrict__ features, const int* __restrict__ coords,
    const float* __restrict__ w_ih, const float* __restrict__ w_hh,
    const float* __restrict__ b_ih, const float* __restrict__ b_hh,
    float* __restrict__ w_ih_T, float* __restrict__ w_hh_T,
    float* __restrict__ biassum, int* __restrict__ map,
    int* __restrict__ cnt, int* __restrict__ mcnt,
    int* __restrict__ chainpk, int* __restrict__ mlist,
    int* __restrict__ slots, float* __restrict__ hfin,
    float* __restrict__ out, int* __restrict__ flags) {
    __shared__ Smem sm;
    int tid = threadIdx.x;
    int bid = blockIdx.x;

    // ---------------- phase P: per-batch build + sort + transpose ----------
    if (bid < 8) {
        int bb = bid;
#pragma unroll
        for (int i = 0; i < 16; i++) sm.pre.cnt16[tid + 512 * i] = 0;
        if (tid == 0) { sm.pre.nch = 0; sm.pre.nmul = 0; }
#pragma unroll
        for (int i = 0; i < 32; i++) map[bb * NRF + tid + 512 * i] = -1;
        __syncthreads();
        int rf[4], pos[4];
#pragma unroll
        for (int e = 0; e < 4; e++) {
            int n = tid + 512 * e;
            int2 cc = ((const int2*)coords)[bb * N + n];
            rf[e] = cc.y * 128 + cc.x;
            int word = rf[e] >> 1, sh = (rf[e] & 1) << 4;
            unsigned int old = atomicAdd(&sm.pre.cnt16[word], 1u << sh);
            pos[e] = (int)((old >> sh) & 0xFFFFu);
            if (pos[e] < MAXLEN)
                slots[((size_t)bb * NRF + rf[e]) * MAXLEN + pos[e]] = n;
        }
        __syncthreads();                    // counts + slot stores visible
#pragma unroll
        for (int e = 0; e < 4; e++) {
            if (pos[e] == 0) {              // chain head
                int j = atomicAdd(&sm.pre.nch, 1);
                int word = rf[e] >> 1, sh = (rf[e] & 1) << 4;
                int len = (int)((sm.pre.cnt16[word] >> sh) & 0xFFFFu);
                if (len > MAXLEN) len = MAXLEN;
                map[bb * NRF + rf[e]] = j;
                int* sl = slots + ((size_t)bb * NRF + rf[e]) * MAXLEN;
                int ev[MAXLEN];
#pragma unroll
                for (int t = 0; t < MAXLEN; t++) {
                    int v = sl[t];
                    ev[t] = (t < len) ? v : 0x7fffffff;
                }
#pragma unroll
                for (int a = 0; a < MAXLEN; a++)   // time-sort
#pragma unroll
                    for (int q = 0; q < MAXLEN - 1; q++) {
                        int u = ev[q], v = ev[q + 1];
                        ev[q] = min(u, v);
                        ev[q + 1] = max(u, v);
                    }
                if (len >= 2) {
                    for (int t = 0; t < len; t++) sl[t] = ev[t];
                    int m = atomicAdd(&sm.pre.nmul, 1);
                    if (m < 1024) mlist[bb * 1024 + m] = j | (rf[e] << 11);
                }
                chainpk[bb * MAXCH + j] = ev[0] | (len << 11);
            }
        }
        __syncthreads();
        if (tid == 0) {
            cnt[bb] = sm.pre.nch;
            mcnt[bb] = (sm.pre.nmul > 1024) ? 1024 : sm.pre.nmul;
        }
    } else {
        int i = (bid - 8) * 512 + tid;     // 504 blocks cover 74240
        if (i < C * 512) {                 // w_ih_T[c][j] = w_ih[j][c]
            int c2 = i >> 9, j = i & 511;
            w_ih_T[i] = w_ih[j * C + c2];
        }
        if (i < HID * 512) {               // w_hh_T[k][j] = w_hh[j][k]
            int k = i >> 9, j = i & 511;
            w_hh_T[i] = w_hh[j * HID + k];
        }
        if (i < 512) biassum[i] = b_ih[i] + b_hh[i];
    }
    gridbar(flags, MAGIC1);

    // ---------------- phase M: recur (multis) then gate0 (singletons) ------
    {
        // stage gate0 weights + bias + slot meta up front
        for (int i = tid; i < C * 128; i += 512)
            ((float4*)sm.mn.ls_w)[i] = ((const float4*)w_ih_T)[i];
        sm.mn.ls_b[tid] = biassum[tid];
        int gbb = bid >> 6;                // 64 gate0 blocks per batch
        int slot0 = (bid & 63) * 32;       // 32 slots per block
        if (tid < 32) {
            int j = slot0 + tid;
            sm.mn.l_pk[tid] = (j < cnt[gbb]) ? chainpk[gbb * MAXCH + j] : -1;
        }

        // recur: bb = bid&7, m-slot = bid>>3 (64 per batch, ~2 chains serial)
        int bb = bid & 7, m0 = bid >> 3;
        int M = mcnt[bb];
        float bs = biassum[tid];
        float wi[16];
        if (m0 < M) {                      // block-uniform
#pragma unroll
            for (int c2 = 0; c2 < 16; c2++) wi[c2] = w_ih_T[c2 * 512 + tid];
        }
        for (int m = m0; m < M; m += 64) {
            int e = mlist[bb * 1024 + m];
            int j = e & 2047, rf = e >> 11;
            size_t idx = (size_t)(bb * MAXCH + j);
            int len = chainpk[bb * MAXCH + j] >> 11;
            const int* sl = slots + ((size_t)bb * NRF + rf) * MAXLEN;  // sorted
            if (tid < 16) sm.mn.x_s[tid] =
                features[((size_t)(bb * N + sl[0])) * C + tid];
            if (tid < 128) sm.mn.c_s[tid] = 0.f;
            __syncthreads();
            for (int t = 0; t < len; t++) {   // len block-uniform
                float a0 = bs, a1 = 0.f, a2 = 0.f, a3 = 0.f;
#pragma unroll
                for (int c2 = 0; c2 < 16; c2++) a0 += wi[c2] * sm.mn.x_s[c2];
                if (t > 0) {
#pragma unroll 8
                    for (int k = 0; k < 128; k += 4) {
                        a0 += w_hh_T[k * 512 + tid]       * sm.mn.h_s[k];
                        a1 += w_hh_T[(k + 1) * 512 + tid] * sm.mn.h_s[k + 1];
                        a2 += w_hh_T[(k + 2) * 512 + tid] * sm.mn.h_s[k + 2];
                        a3 += w_hh_T[(k + 3) * 512 + tid] * sm.mn.h_s[k + 3];
                    }
                }
                sm.mn.g_s[tid] = (a0 + a1) + (a2 + a3);
                __syncthreads();              // gates ready; x_s readers done
                if (tid < 128) {
                    float ig = sigf(sm.mn.g_s[tid]);
                    float fg = sigf(sm.mn.g_s[tid + 128]);
                    float gg = tanhf(sm.mn.g_s[tid + 256]);
                    float og = sigf(sm.mn.g_s[tid + 384]);
                    float cn = fg * sm.mn.c_s[tid] + ig * gg;   // t=0: c=0
                    sm.mn.c_s[tid] = cn;
                    sm.mn.h_s[tid] = og * tanhf(cn);
                }
                if (tid < 16 && t + 1 < len)  // prefetch next x
                    sm.mn.x_s[tid] =
                        features[((size_t)(bb * N + sl[t + 1])) * C + tid];
                __syncthreads();
            }
            if (tid < 128) hfin[idx * HID + tid] = sm.mn.h_s[tid];
            __syncthreads();                  // before LDS reuse by next m
        }
        __syncthreads();                      // staging + l_pk visible

        // gate0: 32 slots/block (4 per wave), singletons only
        int w = tid >> 6, lane = tid & 63;
        int pk[4];
        float f[4];
#pragma unroll
        for (int s2 = 0; s2 < 4; s2++) {   // issue all feature loads first
            pk[s2] = sm.mn.l_pk[w * 4 + s2];
            f[s2] = 0.f;
            if (pk[s2] >= 0 && (pk[s2] >> 11) == 1 && lane < 16)
                f[s2] = features[((size_t)(gbb * N + (pk[s2] & 2047))) * C + lane];
        }
#pragma unroll
        for (int s2 = 0; s2 < 4; s2++) {
            if (pk[s2] < 0 || (pk[s2] >> 11) != 1) continue;
            float ai0 = sm.mn.ls_b[lane],       ai1 = sm.mn.ls_b[lane + 64];
            float ag0 = sm.mn.ls_b[lane + 256], ag1 = sm.mn.ls_b[lane + 320];
            float ao0 = sm.mn.ls_b[lane + 384], ao1 = sm.mn.ls_b[lane + 448];
#pragma unroll
            for (int c2 = 0; c2 < 16; c2++) {
                float xv = __shfl(f[s2], c2, 64);
                ai0 += sm.mn.ls_w[c2 * 512 + lane]       * xv;
                ai1 += sm.mn.ls_w[c2 * 512 + lane + 64]  * xv;
                ag0 += sm.mn.ls_w[c2 * 512 + lane + 256] * xv;
                ag1 += sm.mn.ls_w[c2 * 512 + lane + 320] * xv;
                ao0 += sm.mn.ls_w[c2 * 512 + lane + 384] * xv;
                ao1 += sm.mn.ls_w[c2 * 512 + lane + 448] * xv;
            }
            float cc0 = sigf(ai0) * tanhf(ag0);     // c_prev=0 -> f-gate dead
            float cc1 = sigf(ai1) * tanhf(ag1);
            float h0 = sigf(ao0) * tanhf(cc0);
            float h1 = sigf(ao1) * tanhf(cc1);
            size_t idx = (size_t)(gbb * MAXCH + slot0 + w * 4 + s2);
            hfin[idx * HID + lane] = h0;
            hfin[idx * HID + lane + 64] = h1;
        }
    }
    gridbar(flags, MAGIC2);

    // ---------------- phase S: scatter to dense [B, HID, 128, 128] ---------
    // 1024 (b,y) rows over 512 blocks: two 256-thread halves, one row each.
    // Line-granular gather + register 4x4 transpose (R11/R13-verified).
    {
        int half = tid >> 8;
        int t = tid & 255;
        int row = bid * 2 + half;
        int b = row >> 7, y = row & 127;
        int xq = t & 31;               // x quad: x = 4*xq .. 4*xq+3
        int hg = t >> 5;               // hid group 0..7 (16 hids = one line)
        const int4* mrow = (const int4*)(map + b * NRF + y * 128);
        int4 kk = mrow[xq];
        const float* hb = hfin + (size_t)b * MAXCH * HID + hg * 16;
        float vx[16], vy[16], vz[16], vw[16];
#pragma unroll
        for (int q = 0; q < 4; q++) {
            float4 a = make_float4(0.f, 0.f, 0.f, 0.f);
            if (kk.x >= 0) a = *(const float4*)(hb + (size_t)kk.x * HID + q * 4);
            vx[q * 4 + 0] = a.x; vx[q * 4 + 1] = a.y;
            vx[q * 4 + 2] = a.z; vx[q * 4 + 3] = a.w;
            a = make_float4(0.f, 0.f, 0.f, 0.f);
            if (kk.y >= 0) a = *(const float4*)(hb + (size_t)kk.y * HID + q * 4);
            vy[q * 4 + 0] = a.x; vy[q * 4 + 1] = a.y;
            vy[q * 4 + 2] = a.z; vy[q * 4 + 3] = a.w;
            a = make_float4(0.f, 0.f, 0.f, 0.f);
            if (kk.z >= 0) a = *(const float4*)(hb + (size_t)kk.z * HID + q * 4);
            vz[q * 4 + 0] = a.x; vz[q * 4 + 1] = a.y;
            vz[q * 4 + 2] = a.z; vz[q * 4 + 3] = a.w;
            a = make_float4(0.f, 0.f, 0.f, 0.f);
            if (kk.w >= 0) a = *(const float4*)(hb + (size_t)kk.w * HID + q * 4);
            vw[q * 4 + 0] = a.x; vw[q * 4 + 1] = a.y;
            vw[q * 4 + 2] = a.z; vw[q * 4 + 3] = a.w;
        }
#pragma unroll
        for (int hh = 0; hh < 16; hh++) {
            int hid = hg * 16 + hh;
            f32x4 v = {vx[hh], vy[hh], vz[hh], vw[hh]};
            __builtin_nontemporal_store(
                v, (f32x4*)(out + ((((size_t)b * HID + hid) * 128 + y) * 128)
                            + xq * 4));
        }
    }
}

extern "C" void kernel_launch(void* const* d_in, const int* in_sizes, int n_in,
                              void* d_out, int out_size, void* d_ws, size_t ws_size,
                              hipStream_t stream) {
    const float* features = (const float*)d_in[0];   // [B,N,C] f32
    const int*   coords   = (const int*)d_in[1];     // [B,N,2] i32
    const float* w_ih     = (const float*)d_in[2];   // [512,16]
    const float* w_hh     = (const float*)d_in[3];   // [512,128]
    const float* b_ih     = (const float*)d_in[4];   // [512]
    const float* b_hh     = (const float*)d_in[5];   // [512]
    float* out = (float*)d_out;                      // [B,128,128,128]

    char* ws = (char*)d_ws;
    float* w_ih_T   = (float*)(ws + 0);              //    32768 B
    float* w_hh_T   = (float*)(ws + 32768);          //   262144 B
    float* biassum  = (float*)(ws + 294912);         //     2048 B
    int*   map      = (int*)(ws + 296960);           //   524288 B
    int*   cnt      = (int*)(ws + 821248);           //       64 B
    int*   mcnt     = (int*)(ws + 821312);           //       64 B
    int*   chainpk  = (int*)(ws + 821376);           //    65536 B
    int*   mlist    = (int*)(ws + 886912);           //    32768 B
    int*   slots    = (int*)(ws + 919680);           //  4194304 B
    float* hfin     = (float*)(ws + 5113984);        //  8388608 B
    int*   flags    = (int*)(ws + 13502592);         //     2048 B -> ~13.5 MB

    k_all<<<dim3(NBLK), dim3(512), 0, stream>>>(
        features, coords, w_ih, w_hh, b_ih, b_hh, w_ih_T, w_hh_T, biassum,
        map, cnt, mcnt, chainpk, mlist, slots, hfin, out, flags);
}

// Round 6
// 303.845 us; speedup vs baseline: 1.9193x; 1.9193x over previous
//
#include <hip/hip_runtime.h>
#include <math.h>

#define B 8
#define N 2048
#define C 16
#define HID 128
#define NRF 16384      // 128*128
#define MAXLEN 8
#define MAXCH 2048
#define NBLK 256       // == CU count: 1 block/CU unconditionally co-resident

#define MAGIC1 0x1357BD13
#define MAGIC2 0x2468ACE2

typedef __attribute__((ext_vector_type(4))) float f32x4;  // native vec for nontemporal

__device__ __forceinline__ float sigf(float x) { return 1.f / (1.f + expf(-x)); }

// Poison-tolerant grid barrier (R13-verified under graph capture): block
// publishes flags[bid]=magic (release, agent scope); threads 0..NBLK-1
// spin-acquire on flags[tid]. Distinct magics per barrier -> stale values
// (poison or previous launch's K2) never alias the awaited magic.
__device__ __forceinline__ void gridbar(int* flags, int magic) {
    __syncthreads();
    if (threadIdx.x == 0) {
        __threadfence();   // release all prior global writes (agent scope)
        __hip_atomic_store(&flags[blockIdx.x], magic, __ATOMIC_RELEASE,
                           __HIP_MEMORY_SCOPE_AGENT);
    }
    if (threadIdx.x < NBLK) {
        while (__hip_atomic_load(&flags[threadIdx.x], __ATOMIC_ACQUIRE,
                                 __HIP_MEMORY_SCOPE_AGENT) != magic)
            __builtin_amdgcn_s_sleep(1);
    }
    __syncthreads();
    __threadfence();       // acquire side: drop stale cached lines
}

// LDS union: pre phase = 16-bit-packed counters (32 KB); main phase =
// gate0 weight stage (32 KB) + paired recur state (~6.5 KB). ~41 KB max.
struct SmemPre {
    unsigned int cnt16[NRF / 2];       // two 16-bit counts per word (<=2048 each)
    int nch, nmul;
};
struct SmemMain {
    float ls_w[C * 512];               // 32 KB gate0 weights
    float ls_b[512];
    int   l_pk[64];
    // paired recur: one state set per 256-thread half
    float x_s2[2][16];
    float c_s2[2][HID];
    float h_s2[2][HID];
    float g_s2[2][512];
    int   len_sh[2];
};
union Smem { SmemPre pre; SmemMain mn; };

// R15: fused v3. R14 post-mortem: launch_bounds(512,4) clamped VGPR to 64 ->
// total spill -> 540us. Fixes: (512,2) (R13-measured VGPR 112, no clamp);
// NBLK=256 (1 block/CU co-resident for ANY vgpr -> deadlock-proof barrier);
// recur parallelism recovered by PAIRING: two 256-thread halves per block
// run two chains concurrently in lockstep (each thread owns 2 of 512 gates;
// per-half LDS state; uniform syncthreads via pair-max len). 64 chain
// slots/batch -> ~2 serial rounds, same critical path as 3-kernel version.
// No wcol (R13 spill source) - weights stream from L2 (proven pattern).
__global__ __launch_bounds__(512, 2) void k_all(
    const float* __restrict__ features, const int* __restrict__ coords,
    const float* __restrict__ w_ih, const float* __restrict__ w_hh,
    const float* __restrict__ b_ih, const float* __restrict__ b_hh,
    float* __restrict__ w_ih_T, float* __restrict__ w_hh_T,
    float* __restrict__ biassum, int* __restrict__ map,
    int* __restrict__ cnt, int* __restrict__ mcnt,
    int* __restrict__ chainpk, int* __restrict__ mlist,
    int* __restrict__ slots, float* __restrict__ hfin,
    float* __restrict__ out, int* __restrict__ flags) {
    __shared__ Smem sm;
    int tid = threadIdx.x;
    int bid = blockIdx.x;

    // ---------------- phase P: per-batch build + sort + transpose ----------
    if (bid < 8) {
        int bb = bid;
#pragma unroll
        for (int i = 0; i < 16; i++) sm.pre.cnt16[tid + 512 * i] = 0;
        if (tid == 0) { sm.pre.nch = 0; sm.pre.nmul = 0; }
#pragma unroll
        for (int i = 0; i < 32; i++) map[bb * NRF + tid + 512 * i] = -1;
        __syncthreads();
        int rf[4], pos[4];
#pragma unroll
        for (int e = 0; e < 4; e++) {
            int n = tid + 512 * e;
            int2 cc = ((const int2*)coords)[bb * N + n];
            rf[e] = cc.y * 128 + cc.x;
            int word = rf[e] >> 1, sh = (rf[e] & 1) << 4;
            unsigned int old = atomicAdd(&sm.pre.cnt16[word], 1u << sh);
            pos[e] = (int)((old >> sh) & 0xFFFFu);
            if (pos[e] < MAXLEN)
                slots[((size_t)bb * NRF + rf[e]) * MAXLEN + pos[e]] = n;
        }
        __syncthreads();                    // counts + slot stores visible
#pragma unroll
        for (int e = 0; e < 4; e++) {
            if (pos[e] == 0) {              // chain head
                int j = atomicAdd(&sm.pre.nch, 1);
                int word = rf[e] >> 1, sh = (rf[e] & 1) << 4;
                int len = (int)((sm.pre.cnt16[word] >> sh) & 0xFFFFu);
                if (len > MAXLEN) len = MAXLEN;
                map[bb * NRF + rf[e]] = j;
                int* sl = slots + ((size_t)bb * NRF + rf[e]) * MAXLEN;
                int ev[MAXLEN];
#pragma unroll
                for (int t = 0; t < MAXLEN; t++) {
                    int v = sl[t];
                    ev[t] = (t < len) ? v : 0x7fffffff;
                }
#pragma unroll
                for (int a = 0; a < MAXLEN; a++)   // time-sort
#pragma unroll
                    for (int q = 0; q < MAXLEN - 1; q++) {
                        int u = ev[q], v = ev[q + 1];
                        ev[q] = min(u, v);
                        ev[q + 1] = max(u, v);
                    }
                if (len >= 2) {
                    for (int t = 0; t < len; t++) sl[t] = ev[t];
                    int m = atomicAdd(&sm.pre.nmul, 1);
                    if (m < 1024) mlist[bb * 1024 + m] = j | (rf[e] << 11);
                }
                chainpk[bb * MAXCH + j] = ev[0] | (len << 11);
            }
        }
        __syncthreads();
        if (tid == 0) {
            cnt[bb] = sm.pre.nch;
            mcnt[bb] = (sm.pre.nmul > 1024) ? 1024 : sm.pre.nmul;
        }
    } else {
        int i = (bid - 8) * 512 + tid;     // 248 blocks cover 74240
        if (i < C * 512) {                 // w_ih_T[c][j] = w_ih[j][c]
            int c2 = i >> 9, j = i & 511;
            w_ih_T[i] = w_ih[j * C + c2];
        }
        if (i < HID * 512) {               // w_hh_T[k][j] = w_hh[j][k]
            int k = i >> 9, j = i & 511;
            w_hh_T[i] = w_hh[j * HID + k];
        }
        if (i < 512) biassum[i] = b_ih[i] + b_hh[i];
    }
    gridbar(flags, MAGIC1);

    // ---------------- phase M: paired recur, then gate0 --------------------
    {
        // stage gate0 weights + bias + slot meta up front
        for (int i = tid; i < C * 128; i += 512)
            ((float4*)sm.mn.ls_w)[i] = ((const float4*)w_ih_T)[i];
        sm.mn.ls_b[tid] = biassum[tid];
        int gbb = bid >> 5;                // 32 gate0 blocks per batch
        int slot0 = (bid & 31) * 64;       // 64 slots per block
        if (tid < 64) {
            int j = slot0 + tid;
            sm.mn.l_pk[tid] = (j < cnt[gbb]) ? chainpk[gbb * MAXCH + j] : -1;
        }

        // paired recur: every block; bb = bid&7, slot = bid>>3 (32/batch),
        // two chains per block (one per 256-thread half) in lockstep.
        int bb = bid & 7, slot = bid >> 3;
        int M = mcnt[bb];
        int h = tid >> 8;                  // half 0/1
        int u = tid & 255;                 // lane within half; owns gates u, u+256
        float bs_a = biassum[u];
        float bs_b = biassum[u + 256];
        float wa[16], wb[16];
#pragma unroll
        for (int c2 = 0; c2 < 16; c2++) {
            wa[c2] = w_ih_T[c2 * 512 + u];
            wb[c2] = w_ih_T[c2 * 512 + u + 256];
        }
        int rounds = (M + 63) >> 6;        // block-uniform
        for (int r = 0; r < rounds; r++) {
            int m = r * 64 + slot * 2 + h;
            int len = 0, j = 0;
            const int* sl = slots;         // safe default, only read if len>0
            if (m < M) {
                int e = mlist[bb * 1024 + m];
                j = e & 2047;
                int rf = e >> 11;
                len = chainpk[bb * MAXCH + j] >> 11;
                sl = slots + ((size_t)bb * NRF + rf) * MAXLEN;  // sorted
            }
            if (u == 0) sm.mn.len_sh[h] = len;
            if (u < 16 && len > 0)
                sm.mn.x_s2[h][u] = features[((size_t)(bb * N + sl[0])) * C + u];
            if (u < 128) sm.mn.c_s2[h][u] = 0.f;
            __syncthreads();
            int lenmax = max(sm.mn.len_sh[0], sm.mn.len_sh[1]);  // uniform
            for (int t = 0; t < lenmax; t++) {
                if (t < len) {
                    float a0 = bs_a, b0 = bs_b, a1 = 0.f, b1 = 0.f;
#pragma unroll
                    for (int c2 = 0; c2 < 16; c2++) {
                        float xv = sm.mn.x_s2[h][c2];
                        a0 += wa[c2] * xv;
                        b0 += wb[c2] * xv;
                    }
                    if (t > 0) {
#pragma unroll 8
                        for (int k = 0; k < 128; k += 2) {
                            float h0v = sm.mn.h_s2[h][k];
                            float h1v = sm.mn.h_s2[h][k + 1];
                            a0 += w_hh_T[k * 512 + u]             * h0v;
                            b0 += w_hh_T[k * 512 + u + 256]       * h0v;
                            a1 += w_hh_T[(k + 1) * 512 + u]       * h1v;
                            b1 += w_hh_T[(k + 1) * 512 + u + 256] * h1v;
                        }
                    }
                    sm.mn.g_s2[h][u]       = a0 + a1;
                    sm.mn.g_s2[h][u + 256] = b0 + b1;
                }
                __syncthreads();           // gates ready; x_s2 readers done
                if (u < 128 && t < len) {
                    float ig = sigf(sm.mn.g_s2[h][u]);
                    float fg = sigf(sm.mn.g_s2[h][u + 128]);
                    float gg = tanhf(sm.mn.g_s2[h][u + 256]);
                    float og = sigf(sm.mn.g_s2[h][u + 384]);
                    float cn = fg * sm.mn.c_s2[h][u] + ig * gg;   // t=0: c=0
                    sm.mn.c_s2[h][u] = cn;
                    sm.mn.h_s2[h][u] = og * tanhf(cn);
                }
                if (u < 16 && t + 1 < len) // prefetch next x
                    sm.mn.x_s2[h][u] =
                        features[((size_t)(bb * N + sl[t + 1])) * C + u];
                __syncthreads();
            }
            if (u < 128 && len > 0)
                hfin[((size_t)(bb * MAXCH + j)) * HID + u] = sm.mn.h_s2[h][u];
            __syncthreads();               // before LDS reuse by next round
        }
        __syncthreads();                   // staging + l_pk visible

        // gate0: 64 slots/block (8 per wave), singletons only
        int w = tid >> 6, lane = tid & 63;
        int pk[8];
        float f[8];
#pragma unroll
        for (int s2 = 0; s2 < 8; s2++) {   // issue all feature loads first
            pk[s2] = sm.mn.l_pk[w * 8 + s2];
            f[s2] = 0.f;
            if (pk[s2] >= 0 && (pk[s2] >> 11) == 1 && lane < 16)
                f[s2] = features[((size_t)(gbb * N + (pk[s2] & 2047))) * C + lane];
        }
#pragma unroll
        for (int s2 = 0; s2 < 8; s2++) {
            if (pk[s2] < 0 || (pk[s2] >> 11) != 1) continue;
            float ai0 = sm.mn.ls_b[lane],       ai1 = sm.mn.ls_b[lane + 64];
            float ag0 = sm.mn.ls_b[lane + 256], ag1 = sm.mn.ls_b[lane + 320];
            float ao0 = sm.mn.ls_b[lane + 384], ao1 = sm.mn.ls_b[lane + 448];
#pragma unroll
            for (int c2 = 0; c2 < 16; c2++) {
                float xv = __shfl(f[s2], c2, 64);
                ai0 += sm.mn.ls_w[c2 * 512 + lane]       * xv;
                ai1 += sm.mn.ls_w[c2 * 512 + lane + 64]  * xv;
                ag0 += sm.mn.ls_w[c2 * 512 + lane + 256] * xv;
                ag1 += sm.mn.ls_w[c2 * 512 + lane + 320] * xv;
                ao0 += sm.mn.ls_w[c2 * 512 + lane + 384] * xv;
                ao1 += sm.mn.ls_w[c2 * 512 + lane + 448] * xv;
            }
            float cc0 = sigf(ai0) * tanhf(ag0);     // c_prev=0 -> f-gate dead
            float cc1 = sigf(ai1) * tanhf(ag1);
            float h0 = sigf(ao0) * tanhf(cc0);
            float h1 = sigf(ao1) * tanhf(cc1);
            size_t idx = (size_t)(gbb * MAXCH + slot0 + w * 8 + s2);
            hfin[idx * HID + lane] = h0;
            hfin[idx * HID + lane + 64] = h1;
        }
    }
    gridbar(flags, MAGIC2);

    // ---------------- phase S: scatter to dense [B, HID, 128, 128] ---------
    // 1024 (b,y) rows over 256 blocks: 2 passes x two 256-thread halves.
    // Line-granular gather + register 4x4 transpose (R11/R13-verified).
    {
        int half = tid >> 8;
        int t = tid & 255;
        int xq = t & 31;               // x quad: x = 4*xq .. 4*xq+3
        int hg = t >> 5;               // hid group 0..7 (16 hids = one line)
#pragma unroll
        for (int p2 = 0; p2 < 2; p2++) {
            int row = bid * 4 + p2 * 2 + half;
            int b = row >> 7, y = row & 127;
            const int4* mrow = (const int4*)(map + b * NRF + y * 128);
            int4 kk = mrow[xq];
            const float* hb = hfin + (size_t)b * MAXCH * HID + hg * 16;
            float vx[16], vy[16], vz[16], vw[16];
#pragma unroll
            for (int q = 0; q < 4; q++) {
                float4 a = make_float4(0.f, 0.f, 0.f, 0.f);
                if (kk.x >= 0) a = *(const float4*)(hb + (size_t)kk.x * HID + q * 4);
                vx[q * 4 + 0] = a.x; vx[q * 4 + 1] = a.y;
                vx[q * 4 + 2] = a.z; vx[q * 4 + 3] = a.w;
                a = make_float4(0.f, 0.f, 0.f, 0.f);
                if (kk.y >= 0) a = *(const float4*)(hb + (size_t)kk.y * HID + q * 4);
                vy[q * 4 + 0] = a.x; vy[q * 4 + 1] = a.y;
                vy[q * 4 + 2] = a.z; vy[q * 4 + 3] = a.w;
                a = make_float4(0.f, 0.f, 0.f, 0.f);
                if (kk.z >= 0) a = *(const float4*)(hb + (size_t)kk.z * HID + q * 4);
                vz[q * 4 + 0] = a.x; vz[q * 4 + 1] = a.y;
                vz[q * 4 + 2] = a.z; vz[q * 4 + 3] = a.w;
                a = make_float4(0.f, 0.f, 0.f, 0.f);
                if (kk.w >= 0) a = *(const float4*)(hb + (size_t)kk.w * HID + q * 4);
                vw[q * 4 + 0] = a.x; vw[q * 4 + 1] = a.y;
                vw[q * 4 + 2] = a.z; vw[q * 4 + 3] = a.w;
            }
#pragma unroll
            for (int hh = 0; hh < 16; hh++) {
                int hid = hg * 16 + hh;
                f32x4 v = {vx[hh], vy[hh], vz[hh], vw[hh]};
                __builtin_nontemporal_store(
                    v, (f32x4*)(out + ((((size_t)b * HID + hid) * 128 + y) * 128)
                                + xq * 4));
            }
        }
    }
}

extern "C" void kernel_launch(void* const* d_in, const int* in_sizes, int n_in,
                              void* d_out, int out_size, void* d_ws, size_t ws_size,
                              hipStream_t stream) {
    const float* features = (const float*)d_in[0];   // [B,N,C] f32
    const int*   coords   = (const int*)d_in[1];     // [B,N,2] i32
    const float* w_ih     = (const float*)d_in[2];   // [512,16]
    const float* w_hh     = (const float*)d_in[3];   // [512,128]
    const float* b_ih     = (const float*)d_in[4];   // [512]
    const float* b_hh     = (const float*)d_in[5];   // [512]
    float* out = (float*)d_out;                      // [B,128,128,128]

    char* ws = (char*)d_ws;
    float* w_ih_T   = (float*)(ws + 0);              //    32768 B
    float* w_hh_T   = (float*)(ws + 32768);          //   262144 B
    float* biassum  = (float*)(ws + 294912);         //     2048 B
    int*   map      = (int*)(ws + 296960);           //   524288 B
    int*   cnt      = (int*)(ws + 821248);           //       64 B
    int*   mcnt     = (int*)(ws + 821312);           //       64 B
    int*   chainpk  = (int*)(ws + 821376);           //    65536 B
    int*   mlist    = (int*)(ws + 886912);           //    32768 B
    int*   slots    = (int*)(ws + 919680);           //  4194304 B
    float* hfin     = (float*)(ws + 5113984);        //  8388608 B
    int*   flags    = (int*)(ws + 13502592);         //     1024 B -> ~13.5 MB

    k_all<<<dim3(NBLK), dim3(512), 0, stream>>>(
        features, coords, w_ih, w_hh, b_ih, b_hh, w_ih_T, w_hh_T, biassum,
        map, cnt, mcnt, chainpk, mlist, slots, hfin, out, flags);
}

// Round 7
// 208.256 us; speedup vs baseline: 2.8002x; 1.4590x over previous
//
#include <hip/hip_runtime.h>
#include <math.h>

#define B 8
#define N 2048
#define C 16
#define HID 128
#define NRF 16384      // 128*128
#define MAXLEN 8
#define MAXCH 2048
#define NBLK 256       // == CU count: 1 block/CU unconditionally co-resident
#define FSTRIDE 16     // one flag per 64B line

#define MAGIC1 0x1357BD13
#define MAGIC2 0x2468ACE2

typedef __attribute__((ext_vector_type(4))) float f32x4;  // native vec for nontemporal

__device__ __forceinline__ float sigf(float x) { return 1.f / (1.f + expf(-x)); }

// R16 quiet barrier. R15's version polled with ACQUIRE agent-scope loads:
// per the gfx9 memory model each acquire load carries cache-invalidate
// maintenance -> 65536 pollers emitted an L2-invalidate storm that starved
// the still-working blocks (theory for k_all 230-241us at 5% VALUBusy).
// Fix: RELAXED polls (agent atomics still route to the coherence point for
// visibility; relaxed drops the per-poll invalidate), ONE acquire fence
// after the loop, s_sleep(16) (~0.4us poll period), line-padded flags.
__device__ __forceinline__ void gridbar(int* flags, int magic) {
    __syncthreads();
    if (threadIdx.x == 0) {
        __threadfence();   // release: prior global writes visible before flag
        __hip_atomic_store(&flags[blockIdx.x * FSTRIDE], magic,
                           __ATOMIC_RELAXED, __HIP_MEMORY_SCOPE_AGENT);
    }
    if (threadIdx.x < NBLK) {
        while (__hip_atomic_load(&flags[threadIdx.x * FSTRIDE],
                                 __ATOMIC_RELAXED, __HIP_MEMORY_SCOPE_AGENT)
               != magic)
            __builtin_amdgcn_s_sleep(16);
    }
    __syncthreads();
    __threadfence();       // acquire: one invalidate per wave, after exit
}

// LDS union: pre phase = 16-bit-packed counters (32 KB); main phase =
// gate0 weight stage (32 KB) + paired recur state (~6.5 KB). ~41 KB max.
struct SmemPre {
    unsigned int cnt16[NRF / 2];       // two 16-bit counts per word (<=2048 each)
    int nch, nmul;
};
struct SmemMain {
    float ls_w[C * 512];               // 32 KB gate0 weights
    float ls_b[512];
    int   l_pk[64];
    // paired recur: one state set per 256-thread half
    float x_s2[2][16];
    float c_s2[2][HID];
    float h_s2[2][HID];
    float g_s2[2][512];
    int   len_sh[2];
};
union Smem { SmemPre pre; SmemMain mn; };

// R16: fused v4 == R15 byte-identical except gridbar (single-variable A/B).
// R15 post-mortem: paired recur changed nothing vs R13 (241 vs 230us) ->
// phase M exonerated; barrier poll-storm is the remaining common suspect.
__global__ __launch_bounds__(512, 2) void k_all(
    const float* __restrict__ features, const int* __restrict__ coords,
    const float* __restrict__ w_ih, const float* __restrict__ w_hh,
    const float* __restrict__ b_ih, const float* __restrict__ b_hh,
    float* __restrict__ w_ih_T, float* __restrict__ w_hh_T,
    float* __restrict__ biassum, int* __restrict__ map,
    int* __restrict__ cnt, int* __restrict__ mcnt,
    int* __restrict__ chainpk, int* __restrict__ mlist,
    int* __restrict__ slots, float* __restrict__ hfin,
    float* __restrict__ out, int* __restrict__ flags) {
    __shared__ Smem sm;
    int tid = threadIdx.x;
    int bid = blockIdx.x;

    // ---------------- phase P: per-batch build + sort + transpose ----------
    if (bid < 8) {
        int bb = bid;
#pragma unroll
        for (int i = 0; i < 16; i++) sm.pre.cnt16[tid + 512 * i] = 0;
        if (tid == 0) { sm.pre.nch = 0; sm.pre.nmul = 0; }
#pragma unroll
        for (int i = 0; i < 32; i++) map[bb * NRF + tid + 512 * i] = -1;
        __syncthreads();
        int rf[4], pos[4];
#pragma unroll
        for (int e = 0; e < 4; e++) {
            int n = tid + 512 * e;
            int2 cc = ((const int2*)coords)[bb * N + n];
            rf[e] = cc.y * 128 + cc.x;
            int word = rf[e] >> 1, sh = (rf[e] & 1) << 4;
            unsigned int old = atomicAdd(&sm.pre.cnt16[word], 1u << sh);
            pos[e] = (int)((old >> sh) & 0xFFFFu);
            if (pos[e] < MAXLEN)
                slots[((size_t)bb * NRF + rf[e]) * MAXLEN + pos[e]] = n;
        }
        __syncthreads();                    // counts + slot stores visible
#pragma unroll
        for (int e = 0; e < 4; e++) {
            if (pos[e] == 0) {              // chain head
                int j = atomicAdd(&sm.pre.nch, 1);
                int word = rf[e] >> 1, sh = (rf[e] & 1) << 4;
                int len = (int)((sm.pre.cnt16[word] >> sh) & 0xFFFFu);
                if (len > MAXLEN) len = MAXLEN;
                map[bb * NRF + rf[e]] = j;
                int* sl = slots + ((size_t)bb * NRF + rf[e]) * MAXLEN;
                int ev[MAXLEN];
#pragma unroll
                for (int t = 0; t < MAXLEN; t++) {
                    int v = sl[t];
                    ev[t] = (t < len) ? v : 0x7fffffff;
                }
#pragma unroll
                for (int a = 0; a < MAXLEN; a++)   // time-sort
#pragma unroll
                    for (int q = 0; q < MAXLEN - 1; q++) {
                        int u = ev[q], v = ev[q + 1];
                        ev[q] = min(u, v);
                        ev[q + 1] = max(u, v);
                    }
                if (len >= 2) {
                    for (int t = 0; t < len; t++) sl[t] = ev[t];
                    int m = atomicAdd(&sm.pre.nmul, 1);
                    if (m < 1024) mlist[bb * 1024 + m] = j | (rf[e] << 11);
                }
                chainpk[bb * MAXCH + j] = ev[0] | (len << 11);
            }
        }
        __syncthreads();
        if (tid == 0) {
            cnt[bb] = sm.pre.nch;
            mcnt[bb] = (sm.pre.nmul > 1024) ? 1024 : sm.pre.nmul;
        }
    } else {
        int i = (bid - 8) * 512 + tid;     // 248 blocks cover 74240
        if (i < C * 512) {                 // w_ih_T[c][j] = w_ih[j][c]
            int c2 = i >> 9, j = i & 511;
            w_ih_T[i] = w_ih[j * C + c2];
        }
        if (i < HID * 512) {               // w_hh_T[k][j] = w_hh[j][k]
            int k = i >> 9, j = i & 511;
            w_hh_T[i] = w_hh[j * HID + k];
        }
        if (i < 512) biassum[i] = b_ih[i] + b_hh[i];
    }
    gridbar(flags, MAGIC1);

    // ---------------- phase M: paired recur, then gate0 --------------------
    {
        // stage gate0 weights + bias + slot meta up front
        for (int i = tid; i < C * 128; i += 512)
            ((float4*)sm.mn.ls_w)[i] = ((const float4*)w_ih_T)[i];
        sm.mn.ls_b[tid] = biassum[tid];
        int gbb = bid >> 5;                // 32 gate0 blocks per batch
        int slot0 = (bid & 31) * 64;       // 64 slots per block
        if (tid < 64) {
            int j = slot0 + tid;
            sm.mn.l_pk[tid] = (j < cnt[gbb]) ? chainpk[gbb * MAXCH + j] : -1;
        }

        // paired recur: every block; bb = bid&7, slot = bid>>3 (32/batch),
        // two chains per block (one per 256-thread half) in lockstep.
        int bb = bid & 7, slot = bid >> 3;
        int M = mcnt[bb];
        int h = tid >> 8;                  // half 0/1
        int u = tid & 255;                 // lane within half; owns gates u, u+256
        float bs_a = biassum[u];
        float bs_b = biassum[u + 256];
        float wa[16], wb[16];
#pragma unroll
        for (int c2 = 0; c2 < 16; c2++) {
            wa[c2] = w_ih_T[c2 * 512 + u];
            wb[c2] = w_ih_T[c2 * 512 + u + 256];
        }
        int rounds = (M + 63) >> 6;        // block-uniform
        for (int r = 0; r < rounds; r++) {
            int m = r * 64 + slot * 2 + h;
            int len = 0, j = 0;
            const int* sl = slots;         // safe default, only read if len>0
            if (m < M) {
                int e = mlist[bb * 1024 + m];
                j = e & 2047;
                int rf = e >> 11;
                len = chainpk[bb * MAXCH + j] >> 11;
                sl = slots + ((size_t)bb * NRF + rf) * MAXLEN;  // sorted
            }
            if (u == 0) sm.mn.len_sh[h] = len;
            if (u < 16 && len > 0)
                sm.mn.x_s2[h][u] = features[((size_t)(bb * N + sl[0])) * C + u];
            if (u < 128) sm.mn.c_s2[h][u] = 0.f;
            __syncthreads();
            int lenmax = max(sm.mn.len_sh[0], sm.mn.len_sh[1]);  // uniform
            for (int t = 0; t < lenmax; t++) {
                if (t < len) {
                    float a0 = bs_a, b0 = bs_b, a1 = 0.f, b1 = 0.f;
#pragma unroll
                    for (int c2 = 0; c2 < 16; c2++) {
                        float xv = sm.mn.x_s2[h][c2];
                        a0 += wa[c2] * xv;
                        b0 += wb[c2] * xv;
                    }
                    if (t > 0) {
#pragma unroll 8
                        for (int k = 0; k < 128; k += 2) {
                            float h0v = sm.mn.h_s2[h][k];
                            float h1v = sm.mn.h_s2[h][k + 1];
                            a0 += w_hh_T[k * 512 + u]             * h0v;
                            b0 += w_hh_T[k * 512 + u + 256]       * h0v;
                            a1 += w_hh_T[(k + 1) * 512 + u]       * h1v;
                            b1 += w_hh_T[(k + 1) * 512 + u + 256] * h1v;
                        }
                    }
                    sm.mn.g_s2[h][u]       = a0 + a1;
                    sm.mn.g_s2[h][u + 256] = b0 + b1;
                }
                __syncthreads();           // gates ready; x_s2 readers done
                if (u < 128 && t < len) {
                    float ig = sigf(sm.mn.g_s2[h][u]);
                    float fg = sigf(sm.mn.g_s2[h][u + 128]);
                    float gg = tanhf(sm.mn.g_s2[h][u + 256]);
                    float og = sigf(sm.mn.g_s2[h][u + 384]);
                    float cn = fg * sm.mn.c_s2[h][u] + ig * gg;   // t=0: c=0
                    sm.mn.c_s2[h][u] = cn;
                    sm.mn.h_s2[h][u] = og * tanhf(cn);
                }
                if (u < 16 && t + 1 < len) // prefetch next x
                    sm.mn.x_s2[h][u] =
                        features[((size_t)(bb * N + sl[t + 1])) * C + u];
                __syncthreads();
            }
            if (u < 128 && len > 0)
                hfin[((size_t)(bb * MAXCH + j)) * HID + u] = sm.mn.h_s2[h][u];
            __syncthreads();               // before LDS reuse by next round
        }
        __syncthreads();                   // staging + l_pk visible

        // gate0: 64 slots/block (8 per wave), singletons only
        int w = tid >> 6, lane = tid & 63;
        int pk[8];
        float f[8];
#pragma unroll
        for (int s2 = 0; s2 < 8; s2++) {   // issue all feature loads first
            pk[s2] = sm.mn.l_pk[w * 8 + s2];
            f[s2] = 0.f;
            if (pk[s2] >= 0 && (pk[s2] >> 11) == 1 && lane < 16)
                f[s2] = features[((size_t)(gbb * N + (pk[s2] & 2047))) * C + lane];
        }
#pragma unroll
        for (int s2 = 0; s2 < 8; s2++) {
            if (pk[s2] < 0 || (pk[s2] >> 11) != 1) continue;
            float ai0 = sm.mn.ls_b[lane],       ai1 = sm.mn.ls_b[lane + 64];
            float ag0 = sm.mn.ls_b[lane + 256], ag1 = sm.mn.ls_b[lane + 320];
            float ao0 = sm.mn.ls_b[lane + 384], ao1 = sm.mn.ls_b[lane + 448];
#pragma unroll
            for (int c2 = 0; c2 < 16; c2++) {
                float xv = __shfl(f[s2], c2, 64);
                ai0 += sm.mn.ls_w[c2 * 512 + lane]       * xv;
                ai1 += sm.mn.ls_w[c2 * 512 + lane + 64]  * xv;
                ag0 += sm.mn.ls_w[c2 * 512 + lane + 256] * xv;
                ag1 += sm.mn.ls_w[c2 * 512 + lane + 320] * xv;
                ao0 += sm.mn.ls_w[c2 * 512 + lane + 384] * xv;
                ao1 += sm.mn.ls_w[c2 * 512 + lane + 448] * xv;
            }
            float cc0 = sigf(ai0) * tanhf(ag0);     // c_prev=0 -> f-gate dead
            float cc1 = sigf(ai1) * tanhf(ag1);
            float h0 = sigf(ao0) * tanhf(cc0);
            float h1 = sigf(ao1) * tanhf(cc1);
            size_t idx = (size_t)(gbb * MAXCH + slot0 + w * 8 + s2);
            hfin[idx * HID + lane] = h0;
            hfin[idx * HID + lane + 64] = h1;
        }
    }
    gridbar(flags, MAGIC2);

    // ---------------- phase S: scatter to dense [B, HID, 128, 128] ---------
    // 1024 (b,y) rows over 256 blocks: 2 passes x two 256-thread halves.
    // Line-granular gather + register 4x4 transpose (R11/R13-verified).
    {
        int half = tid >> 8;
        int t = tid & 255;
        int xq = t & 31;               // x quad: x = 4*xq .. 4*xq+3
        int hg = t >> 5;               // hid group 0..7 (16 hids = one line)
#pragma unroll
        for (int p2 = 0; p2 < 2; p2++) {
            int row = bid * 4 + p2 * 2 + half;
            int b = row >> 7, y = row & 127;
            const int4* mrow = (const int4*)(map + b * NRF + y * 128);
            int4 kk = mrow[xq];
            const float* hb = hfin + (size_t)b * MAXCH * HID + hg * 16;
            float vx[16], vy[16], vz[16], vw[16];
#pragma unroll
            for (int q = 0; q < 4; q++) {
                float4 a = make_float4(0.f, 0.f, 0.f, 0.f);
                if (kk.x >= 0) a = *(const float4*)(hb + (size_t)kk.x * HID + q * 4);
                vx[q * 4 + 0] = a.x; vx[q * 4 + 1] = a.y;
                vx[q * 4 + 2] = a.z; vx[q * 4 + 3] = a.w;
                a = make_float4(0.f, 0.f, 0.f, 0.f);
                if (kk.y >= 0) a = *(const float4*)(hb + (size_t)kk.y * HID + q * 4);
                vy[q * 4 + 0] = a.x; vy[q * 4 + 1] = a.y;
                vy[q * 4 + 2] = a.z; vy[q * 4 + 3] = a.w;
                a = make_float4(0.f, 0.f, 0.f, 0.f);
                if (kk.z >= 0) a = *(const float4*)(hb + (size_t)kk.z * HID + q * 4);
                vz[q * 4 + 0] = a.x; vz[q * 4 + 1] = a.y;
                vz[q * 4 + 2] = a.z; vz[q * 4 + 3] = a.w;
                a = make_float4(0.f, 0.f, 0.f, 0.f);
                if (kk.w >= 0) a = *(const float4*)(hb + (size_t)kk.w * HID + q * 4);
                vw[q * 4 + 0] = a.x; vw[q * 4 + 1] = a.y;
                vw[q * 4 + 2] = a.z; vw[q * 4 + 3] = a.w;
            }
#pragma unroll
            for (int hh = 0; hh < 16; hh++) {
                int hid = hg * 16 + hh;
                f32x4 v = {vx[hh], vy[hh], vz[hh], vw[hh]};
                __builtin_nontemporal_store(
                    v, (f32x4*)(out + ((((size_t)b * HID + hid) * 128 + y) * 128)
                                + xq * 4));
            }
        }
    }
}

extern "C" void kernel_launch(void* const* d_in, const int* in_sizes, int n_in,
                              void* d_out, int out_size, void* d_ws, size_t ws_size,
                              hipStream_t stream) {
    const float* features = (const float*)d_in[0];   // [B,N,C] f32
    const int*   coords   = (const int*)d_in[1];     // [B,N,2] i32
    const float* w_ih     = (const float*)d_in[2];   // [512,16]
    const float* w_hh     = (const float*)d_in[3];   // [512,128]
    const float* b_ih     = (const float*)d_in[4];   // [512]
    const float* b_hh     = (const float*)d_in[5];   // [512]
    float* out = (float*)d_out;                      // [B,128,128,128]

    char* ws = (char*)d_ws;
    float* w_ih_T   = (float*)(ws + 0);              //    32768 B
    float* w_hh_T   = (float*)(ws + 32768);          //   262144 B
    float* biassum  = (float*)(ws + 294912);         //     2048 B
    int*   map      = (int*)(ws + 296960);           //   524288 B
    int*   cnt      = (int*)(ws + 821248);           //       64 B
    int*   mcnt     = (int*)(ws + 821312);           //       64 B
    int*   chainpk  = (int*)(ws + 821376);           //    65536 B
    int*   mlist    = (int*)(ws + 886912);           //    32768 B
    int*   slots    = (int*)(ws + 919680);           //  4194304 B
    float* hfin     = (float*)(ws + 5113984);        //  8388608 B
    int*   flags    = (int*)(ws + 13502592);         //    16384 B -> ~13.5 MB

    k_all<<<dim3(NBLK), dim3(512), 0, stream>>>(
        features, coords, w_ih, w_hh, b_ih, b_hh, w_ih_T, w_hh_T, biassum,
        map, cnt, mcnt, chainpk, mlist, slots, hfin, out, flags);
}